// Round 5
// baseline (734.648 us; speedup 1.0000x reference)
//
#include <hip/hip_runtime.h>
#include <cstdint>
#include <cstddef>

#define N 16384
#define NRG 256              // row-groups of 64 rows
#define HID 16
#define F_IN 64
#define F_OUT 32
#define RCHUNK 16            // spmm row chunks
#define RGPC (NRG / RCHUNK)  // 16 rgs per spmm chunk
#define RPC (N / RCHUNK)     // 1024 rows per chunk (fallback)
#define SCH 4                // rowsum column-chunks
#define CB 1024              // pass-1 columns per block
#define RY 32                // pass-1 y-blocks
#define ROWCHUNK (N / RY)    // 512 rows per pass-1 block
#define RPW (ROWCHUNK / 4)   // 128 rows per wave = 2 rgs
#define NPART (RY * 4)       // 128 deg partials

__device__ __forceinline__ unsigned long long readlane64(unsigned long long v, int l) {
  union { unsigned long long u; unsigned int s[2]; } x;
  x.u = v;
  unsigned int lo = __builtin_amdgcn_readlane(x.s[0], l);
  unsigned int hi = __builtin_amdgcn_readlane(x.s[1], l);
  return ((unsigned long long)hi << 32) | lo;
}
__device__ __forceinline__ float readlanef(float v, int l) {
  return __int_as_float(__builtin_amdgcn_readlane(__float_as_int(v), l));
}

// ---------- pass 1: pure-streaming mask build (column-bit words) ----------
// Block: CB=1024 cols x ROWCHUNK rows; wave: 128 rows (2 rgs), all 1024 cols.
// Lane owns 16 cols {jb + k*256 + 4*lane + q}. Per row: 4 x 1KB contiguous
// loads (4KB/row). Bits accumulate in registers (bit r = row rg*64+r).
// deg = popcounts (free). Stores: 8 coalesced uint4 per rg. No LDS/atomics.
__global__ void k_mask_deg(const float* __restrict__ A,
                           unsigned long long* __restrict__ maskC,
                           unsigned int* __restrict__ deg_part) {
  int wave = threadIdx.x >> 6, lane = threadIdx.x & 63;
  int jb = blockIdx.x * CB;
  int r0 = blockIdx.y * ROWCHUNK + wave * RPW;
  const float4* A4 = (const float4*)A;
  unsigned int cnt[4][4];
#pragma unroll
  for (int k = 0; k < 4; ++k)
#pragma unroll
    for (int q = 0; q < 4; ++q) cnt[k][q] = 0;

#pragma unroll 1
  for (int g = 0; g < RPW / 64; ++g) {
    int rbase = r0 + g * 64;
    unsigned int lo[4][4], hi[4][4];
#pragma unroll
    for (int k = 0; k < 4; ++k)
#pragma unroll
      for (int q = 0; q < 4; ++q) { lo[k][q] = 0u; hi[k][q] = 0u; }

#pragma unroll
    for (int rr = 0; rr < 64; rr += 4) {
      float4 v[4][4];
#pragma unroll
      for (int u = 0; u < 4; ++u)
#pragma unroll
        for (int k = 0; k < 4; ++k)
          v[u][k] = A4[(size_t)(rbase + rr + u) * (N / 4) + (jb >> 2) + k * 64 + lane];
#pragma unroll
      for (int u = 0; u < 4; ++u) {
#pragma unroll
        for (int k = 0; k < 4; ++k) {
          if (rr + u < 32) {
            unsigned int m = 1u << (rr + u);
            lo[k][0] |= (v[u][k].x != 0.f) ? m : 0u;
            lo[k][1] |= (v[u][k].y != 0.f) ? m : 0u;
            lo[k][2] |= (v[u][k].z != 0.f) ? m : 0u;
            lo[k][3] |= (v[u][k].w != 0.f) ? m : 0u;
          } else {
            unsigned int m = 1u << (rr + u - 32);
            hi[k][0] |= (v[u][k].x != 0.f) ? m : 0u;
            hi[k][1] |= (v[u][k].y != 0.f) ? m : 0u;
            hi[k][2] |= (v[u][k].z != 0.f) ? m : 0u;
            hi[k][3] |= (v[u][k].w != 0.f) ? m : 0u;
          }
        }
      }
    }
    int rg = rbase >> 6;
    unsigned long long* mrow = maskC + (size_t)rg * N + jb;
#pragma unroll
    for (int k = 0; k < 4; ++k) {
#pragma unroll
      for (int q = 0; q < 4; ++q)
        cnt[k][q] += __popc(lo[k][q]) + __popc(hi[k][q]);
      uint4 s0; s0.x = lo[k][0]; s0.y = hi[k][0]; s0.z = lo[k][1]; s0.w = hi[k][1];
      uint4 s1; s1.x = lo[k][2]; s1.y = hi[k][2]; s1.z = lo[k][3]; s1.w = hi[k][3];
      *(uint4*)(mrow + k * 256 + 4 * lane)     = s0;
      *(uint4*)(mrow + k * 256 + 4 * lane + 2) = s1;
    }
  }
  int widx = blockIdx.y * 4 + wave;
#pragma unroll
  for (int k = 0; k < 4; ++k) {
    uint4 c4; c4.x = cnt[k][0]; c4.y = cnt[k][1]; c4.z = cnt[k][2]; c4.w = cnt[k][3];
    *(uint4*)(deg_part + (size_t)widx * N + jb + k * 256 + 4 * lane) = c4;
  }
}

// fallback (no workspace): column-parallel degree only, atomics
__global__ void k_deg_only(const float* __restrict__ A,
                           unsigned int* __restrict__ deg) {
  int j = blockIdx.x * 256 + threadIdx.x;
  int i0 = blockIdx.y * 512;
  unsigned int cnt = 0;
#pragma unroll 4
  for (int i = i0; i < i0 + 512; ++i) {
    float a = A[(size_t)i * N + j];
    cnt += (a != 0.f) ? 1u : 0u;
  }
  atomicAdd(&deg[j], cnt);
}

// ---------- fused: deg reduce + dinv + z = x@W1 + wz = dinv*z ----------
__global__ void k_dinvz(const unsigned int* __restrict__ deg_part, int nparts,
                        const float* __restrict__ x, const float* __restrict__ W1,
                        float* __restrict__ dinv, float* __restrict__ z,
                        float* __restrict__ wz) {
  int i = blockIdx.x * 256 + threadIdx.x;
  unsigned int dsum = 0;
  for (int w = 0; w < nparts; ++w) dsum += deg_part[(size_t)w * N + i];
  float d = rsqrtf((float)(dsum + 1u));        // +1 self-loop
  dinv[i] = d;
  float zz[16];
#pragma unroll
  for (int c = 0; c < 16; ++c) zz[c] = 0.f;
  const float4* xr = (const float4*)(x + (size_t)i * F_IN);
#pragma unroll
  for (int k4 = 0; k4 < 16; ++k4) {
    float4 v = xr[k4];
#pragma unroll
    for (int c = 0; c < 16; ++c) {
      zz[c] += v.x * W1[(4 * k4 + 0) * HID + c];
      zz[c] += v.y * W1[(4 * k4 + 1) * HID + c];
      zz[c] += v.z * W1[(4 * k4 + 2) * HID + c];
      zz[c] += v.w * W1[(4 * k4 + 3) * HID + c];
    }
  }
  float4* z4 = (float4*)(z + (size_t)i * HID);
  float4* w4 = (float4*)(wz + (size_t)i * HID);
#pragma unroll
  for (int q = 0; q < 4; ++q) {
    float4 a; a.x = zz[4*q]; a.y = zz[4*q+1]; a.z = zz[4*q+2]; a.w = zz[4*q+3];
    z4[q] = a;
    float4 b; b.x = a.x * d; b.y = a.y * d; b.z = a.z * d; b.w = a.w * d;
    w4[q] = b;
  }
}

// ---------- s partials: block = rg, wave = column-chunk ----------
// lane r accumulates s for row rg*64+r over the wave's 4096 columns.
__global__ void k_rowsum_C(const unsigned long long* __restrict__ maskC,
                           const float* __restrict__ dinv,
                           float* __restrict__ s_part) {
  int wave = threadIdx.x >> 6, lane = threadIdx.x & 63;
  int rg = blockIdx.x;
  int cbase = wave * (N / SCH);
  const unsigned long long* mrow = maskC + (size_t)rg * N + cbase;
  const float* dvp = dinv + cbase;
  float acc = 0.f;
#pragma unroll 1
  for (int it = 0; it < (N / SCH) / 64; ++it) {
    unsigned long long wv = mrow[it * 64 + lane];
    float dj = dvp[it * 64 + lane];
    unsigned long long nz = __ballot(wv != 0ull);
    while (nz) {
      int l = __builtin_ctzll(nz);
      nz &= nz - 1;
      unsigned long long word = readlane64(wv, l);
      float dvl = readlanef(dj, l);
      if ((word >> lane) & 1ull) acc += dvl;
    }
  }
  s_part[(size_t)wave * N + rg * 64 + lane] = acc;
}

__global__ void k_rowsum_direct(const float* __restrict__ A,
                                const float* __restrict__ dinv,
                                float* __restrict__ s) {
  int wave = threadIdx.x >> 6, lane = threadIdx.x & 63;
  int i = blockIdx.x * 4 + wave;
  const float* Ar = A + (size_t)i * N;
  float acc = 0.f;
  for (int t = 0; t < N; t += 64) {
    float a = Ar[t + lane];
    if (a != 0.f) acc += dinv[t + lane];
  }
#pragma unroll
  for (int off = 32; off > 0; off >>= 1) acc += __shfl_down(acc, off);
  if (lane == 0) s[i] = acc;
}

// ---------- SpMM partials: thread = column j, per-lane bit walk ----------
__global__ void k_spmm_C(const unsigned long long* __restrict__ maskC,
                         const float* __restrict__ wz,
                         float* __restrict__ t_part) {
  int j = blockIdx.x * 256 + threadIdx.x;
  int rg0 = blockIdx.y * RGPC;
  float acc[16];
#pragma unroll
  for (int c = 0; c < 16; ++c) acc[c] = 0.f;
#pragma unroll 1
  for (int g = 0; g < RGPC; ++g) {
    unsigned long long wv = maskC[(size_t)(rg0 + g) * N + j];   // coalesced
    int rbase = (rg0 + g) * 64;
    while (wv) {
      int b = __builtin_ctzll(wv);
      wv &= wv - 1;
      const float4* wr = (const float4*)(wz + (size_t)(rbase + b) * HID);
#pragma unroll
      for (int q = 0; q < 4; ++q) {
        float4 v = wr[q];
        acc[q * 4 + 0] += v.x; acc[q * 4 + 1] += v.y;
        acc[q * 4 + 2] += v.z; acc[q * 4 + 3] += v.w;
      }
    }
  }
  float4* tp = (float4*)t_part;
#pragma unroll
  for (int q = 0; q < 4; ++q) {
    float4 v = make_float4(acc[q * 4 + 0], acc[q * 4 + 1],
                           acc[q * 4 + 2], acc[q * 4 + 3]);
    tp[((size_t)blockIdx.y * 4 + q) * N + j] = v;   // coalesced
  }
}

__global__ void k_spmm_direct(const float* __restrict__ A,
                              const float* __restrict__ wz,
                              float* __restrict__ t_part) {
  int j = blockIdx.x * 256 + threadIdx.x;
  int i0 = blockIdx.y * RPC;
  float acc[16];
#pragma unroll
  for (int c = 0; c < 16; ++c) acc[c] = 0.f;
  for (int i = i0; i < i0 + RPC; ++i) {
    float a = A[(size_t)i * N + j];
    if (a != 0.f) {
      const float4* wr = (const float4*)(wz + (size_t)i * HID);
#pragma unroll
      for (int q = 0; q < 4; ++q) {
        float4 v = wr[q];
        acc[q * 4 + 0] += v.x; acc[q * 4 + 1] += v.y;
        acc[q * 4 + 2] += v.z; acc[q * 4 + 3] += v.w;
      }
    }
  }
  float4* tp = (float4*)t_part;
#pragma unroll
  for (int q = 0; q < 4; ++q) {
    float4 v = make_float4(acc[q * 4 + 0], acc[q * 4 + 1],
                           acc[q * 4 + 2], acc[q * 4 + 3]);
    tp[((size_t)blockIdx.y * 4 + q) * N + j] = v;
  }
}

// ---------- combine partials, relu, u partial per block ----------
__global__ void k_combine(const float* __restrict__ t_part,
                          const float* __restrict__ z,
                          const float* __restrict__ dinv,
                          const float* __restrict__ sp, int nsch,
                          const float* __restrict__ b1,
                          float* __restrict__ u_part) {
  int j = blockIdx.x * 256 + threadIdx.x;
  int lane = threadIdx.x & 63, wave = threadIdx.x >> 6;
  const float4* tp = (const float4*)t_part;
  float acc[16];
#pragma unroll
  for (int c = 0; c < 16; ++c) acc[c] = 0.f;
#pragma unroll
  for (int ch = 0; ch < RCHUNK; ++ch) {
#pragma unroll
    for (int q = 0; q < 4; ++q) {
      float4 v = tp[((size_t)ch * 4 + q) * N + j];
      acc[q * 4 + 0] += v.x; acc[q * 4 + 1] += v.y;
      acc[q * 4 + 2] += v.z; acc[q * 4 + 3] += v.w;
    }
  }
  float zz[16];
  const float4* zr = (const float4*)(z + (size_t)j * HID);
#pragma unroll
  for (int q = 0; q < 4; ++q) {
    float4 v = zr[q];
    zz[q * 4 + 0] = v.x; zz[q * 4 + 1] = v.y; zz[q * 4 + 2] = v.z; zz[q * 4 + 3] = v.w;
  }
  float sv = 0.f;
  for (int sc = 0; sc < nsch; ++sc) sv += sp[(size_t)sc * N + j];
  float d = dinv[j];
  float rj = d * (d + sv);
  float uc[16];
#pragma unroll
  for (int c = 0; c < 16; ++c) {
    float pre = d * (d * zz[c] + acc[c]) + b1[c];
    float h = pre > 0.f ? pre : 0.f;
    uc[c] = rj * h;
  }
#pragma unroll
  for (int c = 0; c < 16; ++c) {
#pragma unroll
    for (int off = 32; off > 0; off >>= 1) uc[c] += __shfl_down(uc[c], off);
  }
  __shared__ float lds[4][16];
  if (lane == 0) {
#pragma unroll
    for (int c = 0; c < 16; ++c) lds[wave][c] = uc[c];
  }
  __syncthreads();
  if (threadIdx.x < 16) {
    float a = lds[0][threadIdx.x] + lds[1][threadIdx.x] +
              lds[2][threadIdx.x] + lds[3][threadIdx.x];
    u_part[blockIdx.x * 16 + threadIdx.x] = a;
  }
}

// ---------- final: u = sum u_part; out = u @ W2 + N*b2 ----------
__global__ void k_final(const float* __restrict__ u_part,
                        const float* __restrict__ W2,
                        const float* __restrict__ b2,
                        float* __restrict__ out) {
  __shared__ float u[16];
  int t = threadIdx.x;
  if (t < 16) {
    float a = 0.f;
    for (int b = 0; b < 64; ++b) a += u_part[b * 16 + t];
    u[t] = a;
  }
  __syncthreads();
  if (t < 32) {
    float o = (float)N * b2[t];
#pragma unroll
    for (int c = 0; c < 16; ++c) o += u[c] * W2[c * F_OUT + t];
    out[t] = o;
  }
}

extern "C" void kernel_launch(void* const* d_in, const int* in_sizes, int n_in,
                              void* d_out, int out_size, void* d_ws, size_t ws_size,
                              hipStream_t stream) {
  const float* A  = (const float*)d_in[0];
  const float* x  = (const float*)d_in[1];
  const float* W1 = (const float*)d_in[2];
  const float* b1 = (const float*)d_in[3];
  const float* W2 = (const float*)d_in[4];
  const float* b2 = (const float*)d_in[5];
  float* out = (float*)d_out;

  char* ws = (char*)d_ws;
  size_t off = 0;
  auto alloc = [&](size_t bytes) {
    char* p = ws + off;
    off += (bytes + 255) & ~(size_t)255;
    return p;
  };

  unsigned int* deg_part = (unsigned int*)alloc((size_t)NPART * N * 4);
  float* dinv       = (float*)alloc((size_t)N * 4);
  float* s_part     = (float*)alloc((size_t)SCH * N * 4);
  float* z          = (float*)alloc((size_t)N * HID * 4);
  float* wz         = (float*)alloc((size_t)N * HID * 4);
  float* u_part     = (float*)alloc(64 * 16 * 4);
  float* t_part     = (float*)alloc((size_t)RCHUNK * N * HID * 4);
  unsigned long long* maskC = (unsigned long long*)alloc((size_t)NRG * N * 8);
  bool use_mask = (ws_size >= off);   // ~59 MB needed for the mask path

  if (use_mask) {
    k_mask_deg<<<dim3(N / CB, RY), 256, 0, stream>>>(A, maskC, deg_part);
    k_dinvz<<<N / 256, 256, 0, stream>>>(deg_part, NPART, x, W1, dinv, z, wz);
    k_rowsum_C<<<NRG, 256, 0, stream>>>(maskC, dinv, s_part);
    k_spmm_C<<<dim3(64, RCHUNK), 256, 0, stream>>>(maskC, wz, t_part);
    k_combine<<<64, 256, 0, stream>>>(t_part, z, dinv, s_part, SCH, b1, u_part);
  } else {
    hipMemsetAsync(deg_part, 0, (size_t)N * 4, stream);
    k_deg_only<<<dim3(64, 32), 256, 0, stream>>>(A, deg_part);
    k_dinvz<<<N / 256, 256, 0, stream>>>(deg_part, 1, x, W1, dinv, z, wz);
    k_rowsum_direct<<<N / 4, 256, 0, stream>>>(A, dinv, s_part);
    k_spmm_direct<<<dim3(64, RCHUNK), 256, 0, stream>>>(A, wz, t_part);
    k_combine<<<64, 256, 0, stream>>>(t_part, z, dinv, s_part, 1, b1, u_part);
  }
  k_final<<<1, 64, 0, stream>>>(u_part, W2, b2, out);
}

// Round 6
// 351.380 us; speedup vs baseline: 2.0908x; 2.0908x over previous
//
#include <hip/hip_runtime.h>
#include <cstdint>
#include <cstddef>

#define N 16384
#define NWORDS 256      // N/64 mask words per row
#define HID 16
#define F_IN 64
#define F_OUT 32
#define RCHUNK 16
#define RPC (N / RCHUNK)     // 1024 rows per spmm chunk
#define PCH 8                // p-chunks for rowsum partials
#define PW (NWORDS / PCH)    // 32 p-words per chunk
#define CB 1024              // pass-1 columns per block
#define NXB (N / CB)         // 16 x-blocks
#define RY 32                // pass-1 y-blocks
#define ROWCHUNK (N / RY)    // 512 rows per pass-1 block
#define RPW (ROWCHUNK / 4)   // 128 rows per pass-1 wave
#define NPART (RY * 4)       // 128 deg partials

// permuted column mapping: word p, bit b  ->  column (p>>2)*256 + 4*b + (p&3)
__device__ __forceinline__ int perm_col(int p, int b) {
  return ((p >> 2) << 8) + (b << 2) + (p & 3);
}

__device__ __forceinline__ unsigned long long readlane64(unsigned long long v, int l) {
  union { unsigned long long u; unsigned int s[2]; } x;
  x.u = v;
  unsigned int lo = __builtin_amdgcn_readlane(x.s[0], l);
  unsigned int hi = __builtin_amdgcn_readlane(x.s[1], l);
  return ((unsigned long long)hi << 32) | lo;
}

// ---------- pass 1: column-block streaming, 4KB/row-visit ----------
// Block: CB=1024 cols x ROWCHUNK rows; wave: RPW=128 rows, all 1024 cols.
// Lane loads 4 float4 (cols jb + k*256 + 4*lane + q). 4-row x 16-load
// batches (#pragma unroll 1 -> no spill). Ballots -> LDS stage -> coalesced
// column-major flush. Degrees in registers, uint4 flush. No atomics.
__global__ void k_mask_deg(const float* __restrict__ A,
                           unsigned long long* __restrict__ maskT,
                           unsigned int* __restrict__ deg_part) {
  int wave = threadIdx.x >> 6, lane = threadIdx.x & 63;
  int jb = blockIdx.x * CB;
  int p0 = blockIdx.x * 16;
  int r0 = blockIdx.y * ROWCHUNK + wave * RPW;
  const float4* A4 = (const float4*)A;
  size_t colbase = (size_t)(jb >> 2) + lane;
  unsigned int cnt[4][4];
#pragma unroll
  for (int k = 0; k < 4; ++k)
#pragma unroll
    for (int q = 0; q < 4; ++q) cnt[k][q] = 0u;
  __shared__ unsigned long long st[4][16][64];   // [wave][word][row-in-group]

#pragma unroll 1
  for (int rb = 0; rb < RPW; rb += 64) {
    int rbase = r0 + rb;
#pragma unroll 1
    for (int g = 0; g < 64; g += 4) {
      float4 v[4][4];
#pragma unroll
      for (int u = 0; u < 4; ++u)
#pragma unroll
        for (int k = 0; k < 4; ++k)
          v[u][k] = A4[(size_t)(rbase + g + u) * (N / 4) + colbase + k * 64];
#pragma unroll
      for (int u = 0; u < 4; ++u) {
#pragma unroll
        for (int k = 0; k < 4; ++k) {
          bool n0 = (v[u][k].x != 0.f), n1 = (v[u][k].y != 0.f);
          bool n2 = (v[u][k].z != 0.f), n3 = (v[u][k].w != 0.f);
          unsigned long long b0 = __ballot(n0);
          unsigned long long b1 = __ballot(n1);
          unsigned long long b2 = __ballot(n2);
          unsigned long long b3 = __ballot(n3);
          cnt[k][0] += n0 ? 1u : 0u;  cnt[k][1] += n1 ? 1u : 0u;
          cnt[k][2] += n2 ? 1u : 0u;  cnt[k][3] += n3 ? 1u : 0u;
          if (lane < 4) {
            unsigned long long bq = (lane == 0) ? b0 : (lane == 1) ? b1
                                  : (lane == 2) ? b2 : b3;
            st[wave][k * 4 + lane][g + u] = bq;
          }
        }
      }
    }
    // flush 64 rows x 16 words: coalesced 512B column-major stores
#pragma unroll
    for (int w = 0; w < 16; ++w)
      maskT[(size_t)(p0 + w) * N + rbase + lane] = st[wave][w][lane];
  }
  int widx = blockIdx.y * 4 + wave;
#pragma unroll
  for (int k = 0; k < 4; ++k) {
    uint4 c4; c4.x = cnt[k][0]; c4.y = cnt[k][1]; c4.z = cnt[k][2]; c4.w = cnt[k][3];
    *(uint4*)(deg_part + (size_t)widx * N + jb + k * 256 + 4 * lane) = c4;
  }
}

// fallback (no workspace): column-parallel degree only, atomics
__global__ void k_deg_only(const float* __restrict__ A,
                           unsigned int* __restrict__ deg) {
  int j = blockIdx.x * 256 + threadIdx.x;
  int i0 = blockIdx.y * 512;
  unsigned int cnt = 0;
#pragma unroll 4
  for (int i = i0; i < i0 + 512; ++i) {
    float a = A[(size_t)i * N + j];
    cnt += (a != 0.f) ? 1u : 0u;
  }
  atomicAdd(&deg[j], cnt);
}

// ---------- fused: deg reduce + dinv + z = x@W1 + wz = dinv*z ----------
__global__ void k_dinvz(const unsigned int* __restrict__ deg_part, int nparts,
                        const float* __restrict__ x, const float* __restrict__ W1,
                        float* __restrict__ dinv, float* __restrict__ z,
                        float* __restrict__ wz) {
  int i = blockIdx.x * 64 + threadIdx.x;
  unsigned int dsum = 0;
#pragma unroll 8
  for (int w = 0; w < nparts; ++w) dsum += deg_part[(size_t)w * N + i];
  float d = rsqrtf((float)(dsum + 1u));        // +1 self-loop
  dinv[i] = d;
  float zz[16];
#pragma unroll
  for (int c = 0; c < 16; ++c) zz[c] = 0.f;
  const float4* xr = (const float4*)(x + (size_t)i * F_IN);
#pragma unroll
  for (int k4 = 0; k4 < 16; ++k4) {
    float4 v = xr[k4];
#pragma unroll
    for (int c = 0; c < 16; ++c) {
      zz[c] += v.x * W1[(4 * k4 + 0) * HID + c];
      zz[c] += v.y * W1[(4 * k4 + 1) * HID + c];
      zz[c] += v.z * W1[(4 * k4 + 2) * HID + c];
      zz[c] += v.w * W1[(4 * k4 + 3) * HID + c];
    }
  }
  float4* z4 = (float4*)(z + (size_t)i * HID);
  float4* w4 = (float4*)(wz + (size_t)i * HID);
#pragma unroll
  for (int q = 0; q < 4; ++q) {
    float4 a; a.x = zz[4*q]; a.y = zz[4*q+1]; a.z = zz[4*q+2]; a.w = zz[4*q+3];
    z4[q] = a;
    float4 b; b.x = a.x * d; b.y = a.y * d; b.z = a.z * d; b.w = a.w * d;
    w4[q] = b;
  }
}

// ---------- s partials: lane owns a row, iterate a p-chunk coalesced ----------
__global__ void k_rowsum_T(const unsigned long long* __restrict__ maskT,
                           const float* __restrict__ dinv,
                           float* __restrict__ s_part) {
  int wave = threadIdx.x >> 6, lane = threadIdx.x & 63;
  int rg = blockIdx.x >> 1;                    // row group [0,256)
  int pc = (blockIdx.x & 1) * 4 + wave;        // p-chunk [0,8)
  int row = rg * 64 + lane;
  int pbase = pc * PW;
  float acc = 0.f;
#pragma unroll 1
  for (int b = 0; b < PW / 8; ++b) {
    unsigned long long w[8];
#pragma unroll
    for (int u = 0; u < 8; ++u)
      w[u] = maskT[(size_t)(pbase + b * 8 + u) * N + row];
#pragma unroll
    for (int u = 0; u < 8; ++u) {
      int p = pbase + b * 8 + u;
      unsigned long long wd = w[u];
      while (wd) {
        int bb = __builtin_ctzll(wd);
        wd &= wd - 1;
        acc += dinv[perm_col(p, bb)];
      }
    }
  }
  s_part[(size_t)pc * N + row] = acc;
}

__global__ void k_rowsum_direct(const float* __restrict__ A,
                                const float* __restrict__ dinv,
                                float* __restrict__ s) {
  int wave = threadIdx.x >> 6, lane = threadIdx.x & 63;
  int i = blockIdx.x * 4 + wave;
  const float* Ar = A + (size_t)i * N;
  float acc = 0.f;
  for (int t = 0; t < N; t += 64) {
    float a = Ar[t + lane];
    if (a != 0.f) acc += dinv[t + lane];
  }
#pragma unroll
  for (int off = 32; off > 0; off >>= 1) acc += __shfl_down(acc, off);
  if (lane == 0) s[i] = acc;
}

// ---------- SpMM partials: wave owns word-position p; rowmask walk ----------
__global__ void k_spmm_T(const unsigned long long* __restrict__ maskT,
                         const float* __restrict__ wz,
                         float* __restrict__ t_part) {
  int p = blockIdx.x * 4 + (threadIdx.x >> 6); // word position [0,256)
  int lane = threadIdx.x & 63;
  int i0 = blockIdx.y * RPC;
  const unsigned long long* mcol = maskT + (size_t)p * N + i0;
  float acc[16];
#pragma unroll
  for (int c = 0; c < 16; ++c) acc[c] = 0.f;
  unsigned long long wv = mcol[lane];          // batch 0, coalesced 512B
#pragma unroll 1
  for (int batch = 0; batch < RPC / 64; ++batch) {
    unsigned long long wnext = (batch + 1 < RPC / 64)
                             ? mcol[(batch + 1) * 64 + lane] : 0ull;
    int ib = i0 + batch * 64;
    unsigned long long rowmask = __ballot(wv != 0ull);
    while (rowmask) {
      int l = __builtin_ctzll(rowmask);
      rowmask &= rowmask - 1;
      unsigned long long wd = readlane64(wv, l);   // uniform word for row ib+l
      if ((wd >> lane) & 1ull) {
        const float4* wr = (const float4*)(wz + (size_t)(ib + l) * HID);
#pragma unroll
        for (int q = 0; q < 4; ++q) {
          float4 v = wr[q];
          acc[q * 4 + 0] += v.x; acc[q * 4 + 1] += v.y;
          acc[q * 4 + 2] += v.z; acc[q * 4 + 3] += v.w;
        }
      }
    }
    wv = wnext;
  }
  int t = blockIdx.x * 256 + threadIdx.x;      // = p*64 + lane
  float4* tp = (float4*)t_part;
#pragma unroll
  for (int q = 0; q < 4; ++q) {
    float4 v = make_float4(acc[q * 4 + 0], acc[q * 4 + 1],
                           acc[q * 4 + 2], acc[q * 4 + 3]);
    tp[((size_t)blockIdx.y * 4 + q) * N + t] = v;   // coalesced
  }
}

__global__ void k_spmm_direct(const float* __restrict__ A,
                              const float* __restrict__ wz,
                              float* __restrict__ t_part) {
  int j = blockIdx.x * 256 + threadIdx.x;
  int i0 = blockIdx.y * RPC;
  float acc[16];
#pragma unroll
  for (int c = 0; c < 16; ++c) acc[c] = 0.f;
  for (int i = i0; i < i0 + RPC; ++i) {
    float a = A[(size_t)i * N + j];
    if (a != 0.f) {
      const float4* wr = (const float4*)(wz + (size_t)i * HID);
#pragma unroll
      for (int q = 0; q < 4; ++q) {
        float4 v = wr[q];
        acc[q * 4 + 0] += v.x; acc[q * 4 + 1] += v.y;
        acc[q * 4 + 2] += v.z; acc[q * 4 + 3] += v.w;
      }
    }
  }
  float4* tp = (float4*)t_part;
#pragma unroll
  for (int q = 0; q < 4; ++q) {
    float4 v = make_float4(acc[q * 4 + 0], acc[q * 4 + 1],
                           acc[q * 4 + 2], acc[q * 4 + 3]);
    tp[((size_t)blockIdx.y * 4 + q) * N + j] = v;
  }
}

// ---------- combine partials, relu, u partial per block (64-thr blocks) ----------
__global__ void k_combine(const float* __restrict__ t_part,
                          const float* __restrict__ z,
                          const float* __restrict__ dinv,
                          const float* __restrict__ sp, int nsch,
                          const float* __restrict__ b1,
                          float* __restrict__ u_part, int perm) {
  int t = blockIdx.x * 64 + threadIdx.x;
  int lane = threadIdx.x & 63;
  int col = perm ? perm_col(t >> 6, t & 63) : t;
  const float4* tp = (const float4*)t_part;
  float acc[16];
#pragma unroll
  for (int c = 0; c < 16; ++c) acc[c] = 0.f;
#pragma unroll
  for (int ch = 0; ch < RCHUNK; ++ch) {
#pragma unroll
    for (int q = 0; q < 4; ++q) {
      float4 v = tp[((size_t)ch * 4 + q) * N + t];
      acc[q * 4 + 0] += v.x; acc[q * 4 + 1] += v.y;
      acc[q * 4 + 2] += v.z; acc[q * 4 + 3] += v.w;
    }
  }
  float zz[16];
  const float4* zr = (const float4*)(z + (size_t)col * HID);
#pragma unroll
  for (int q = 0; q < 4; ++q) {
    float4 v = zr[q];
    zz[q * 4 + 0] = v.x; zz[q * 4 + 1] = v.y; zz[q * 4 + 2] = v.z; zz[q * 4 + 3] = v.w;
  }
  float sv = 0.f;
#pragma unroll 8
  for (int sc = 0; sc < nsch; ++sc) sv += sp[(size_t)sc * N + col];
  float d = dinv[col];
  float rj = d * (d + sv);
  float uc[16];
#pragma unroll
  for (int c = 0; c < 16; ++c) {
    float pre = d * (d * zz[c] + acc[c]) + b1[c];
    float h = pre > 0.f ? pre : 0.f;
    uc[c] = rj * h;
  }
#pragma unroll
  for (int c = 0; c < 16; ++c) {
#pragma unroll
    for (int off = 32; off > 0; off >>= 1) uc[c] += __shfl_down(uc[c], off);
  }
  if (lane == 0) {
#pragma unroll
    for (int c = 0; c < 16; ++c) u_part[blockIdx.x * 16 + c] = uc[c];
  }
}

// ---------- final: u = sum of 256 u_part blocks; out = u @ W2 + N*b2 ----------
__global__ void k_final(const float* __restrict__ u_part,
                        const float* __restrict__ W2,
                        const float* __restrict__ b2,
                        float* __restrict__ out) {
  __shared__ float red[16][17];
  __shared__ float u[16];
  int t = threadIdx.x;                 // 256 threads
  int c = t & 15, g = t >> 4;          // 16 groups x 16 blocks each
  float a = 0.f;
#pragma unroll
  for (int b = 0; b < 16; ++b) a += u_part[(size_t)(g * 16 + b) * 16 + c];
  red[g][c] = a;
  __syncthreads();
  if (t < 16) {
    float s = 0.f;
#pragma unroll
    for (int g2 = 0; g2 < 16; ++g2) s += red[g2][t];
    u[t] = s;
  }
  __syncthreads();
  if (t < 32) {
    float o = (float)N * b2[t];
#pragma unroll
    for (int c2 = 0; c2 < 16; ++c2) o += u[c2] * W2[c2 * F_OUT + t];
    out[t] = o;
  }
}

extern "C" void kernel_launch(void* const* d_in, const int* in_sizes, int n_in,
                              void* d_out, int out_size, void* d_ws, size_t ws_size,
                              hipStream_t stream) {
  const float* A  = (const float*)d_in[0];
  const float* x  = (const float*)d_in[1];
  const float* W1 = (const float*)d_in[2];
  const float* b1 = (const float*)d_in[3];
  const float* W2 = (const float*)d_in[4];
  const float* b2 = (const float*)d_in[5];
  float* out = (float*)d_out;

  char* ws = (char*)d_ws;
  size_t off = 0;
  auto alloc = [&](size_t bytes) {
    char* p = ws + off;
    off += (bytes + 255) & ~(size_t)255;
    return p;
  };

  unsigned int* deg_part = (unsigned int*)alloc((size_t)NPART * N * 4);
  float* dinv       = (float*)alloc((size_t)N * 4);
  float* s_part     = (float*)alloc((size_t)PCH * N * 4);
  float* z          = (float*)alloc((size_t)N * HID * 4);
  float* wz         = (float*)alloc((size_t)N * HID * 4);
  float* u_part     = (float*)alloc(256 * 16 * 4);
  float* t_part     = (float*)alloc((size_t)RCHUNK * N * HID * 4);
  unsigned long long* maskT = (unsigned long long*)alloc((size_t)N * NWORDS * 8);
  bool use_mask = (ws_size >= off);   // ~59 MB needed for the mask path

  if (use_mask) {
    k_mask_deg<<<dim3(NXB, RY), 256, 0, stream>>>(A, maskT, deg_part);
    k_dinvz<<<N / 64, 64, 0, stream>>>(deg_part, NPART, x, W1, dinv, z, wz);
    k_rowsum_T<<<512, 256, 0, stream>>>(maskT, dinv, s_part);
    k_spmm_T<<<dim3(64, RCHUNK), 256, 0, stream>>>(maskT, wz, t_part);
    k_combine<<<N / 64, 64, 0, stream>>>(t_part, z, dinv, s_part, PCH, b1, u_part, 1);
  } else {
    hipMemsetAsync(deg_part, 0, (size_t)N * 4, stream);
    k_deg_only<<<dim3(64, 32), 256, 0, stream>>>(A, deg_part);
    k_dinvz<<<N / 64, 64, 0, stream>>>(deg_part, 1, x, W1, dinv, z, wz);
    k_rowsum_direct<<<N / 4, 256, 0, stream>>>(A, dinv, s_part);
    k_spmm_direct<<<dim3(64, RCHUNK), 256, 0, stream>>>(A, wz, t_part);
    k_combine<<<N / 64, 64, 0, stream>>>(t_part, z, dinv, s_part, 1, b1, u_part, 0);
  }
  k_final<<<1, 256, 0, stream>>>(u_part, W2, b2, out);
}

// Round 7
// 331.563 us; speedup vs baseline: 2.2157x; 1.0598x over previous
//
#include <hip/hip_runtime.h>
#include <cstdint>
#include <cstddef>

#define N 16384
#define NWORDS 256      // N/64 mask words per row
#define HID 16
#define F_IN 64
#define F_OUT 32
#define RCHUNK 16
#define RPC (N / RCHUNK)     // 1024 rows per spmm chunk
#define PCH 8                // p-chunks for rowsum partials
#define PW (NWORDS / PCH)    // 32 p-words per chunk
#define CB 2048              // pass-1 columns per block
#define NXB (N / CB)         // 8 x-blocks
#define RY 64                // pass-1 y-blocks
#define ROWCHUNK (N / RY)    // 256 rows per pass-1 block (64 per wave)
#define NPART RY             // 64 deg partials (block-reduced)

// permuted column mapping: word p, bit b  ->  column (p>>2)*256 + 4*b + (p&3)
__device__ __forceinline__ int perm_col(int p, int b) {
  return ((p >> 2) << 8) + (b << 2) + (p & 3);
}

__device__ __forceinline__ unsigned long long readlane64(unsigned long long v, int l) {
  union { unsigned long long u; unsigned int s[2]; } x;
  x.u = v;
  unsigned int lo = __builtin_amdgcn_readlane(x.s[0], l);
  unsigned int hi = __builtin_amdgcn_readlane(x.s[1], l);
  return ((unsigned long long)hi << 32) | lo;
}

// ---------- pass 1: column-block streaming, 8KB/row-visit ----------
// Block: CB=2048 cols x 256 rows; wave: 64 rows, all 2048 cols.
// Lane loads 8 float4 (cols jb + k*256 + 4*lane + q), 2-row x 16-load
// batches (#pragma unroll 1 -> no spill). Ballots -> LDS stage -> coalesced
// column-major flush. Degrees in registers -> LDS block-reduce -> one
// partial per block. No atomics.
__global__ __launch_bounds__(256, 2)
void k_mask_deg(const float* __restrict__ A,
                unsigned long long* __restrict__ maskT,
                unsigned int* __restrict__ deg_part) {
  int wave = threadIdx.x >> 6, lane = threadIdx.x & 63;
  int jb = blockIdx.x * CB;
  int p0 = blockIdx.x * 32;
  int r0 = blockIdx.y * ROWCHUNK + wave * 64;
  const float4* A4 = (const float4*)A;
  size_t colbase = (size_t)(jb >> 2) + lane;
  unsigned int cnt[8][4];
#pragma unroll
  for (int k = 0; k < 8; ++k)
#pragma unroll
    for (int q = 0; q < 4; ++q) cnt[k][q] = 0u;
  __shared__ unsigned long long st[4][32][64];   // [wave][word][row] = 64 KB

#pragma unroll 1
  for (int g = 0; g < 64; g += 2) {
    float4 v[2][8];
#pragma unroll
    for (int u = 0; u < 2; ++u)
#pragma unroll
      for (int k = 0; k < 8; ++k)
        v[u][k] = A4[(size_t)(r0 + g + u) * (N / 4) + colbase + k * 64];
#pragma unroll
    for (int u = 0; u < 2; ++u) {
#pragma unroll
      for (int k = 0; k < 8; ++k) {
        bool n0 = (v[u][k].x != 0.f), n1 = (v[u][k].y != 0.f);
        bool n2 = (v[u][k].z != 0.f), n3 = (v[u][k].w != 0.f);
        unsigned long long b0 = __ballot(n0);
        unsigned long long b1 = __ballot(n1);
        unsigned long long b2 = __ballot(n2);
        unsigned long long b3 = __ballot(n3);
        cnt[k][0] += n0 ? 1u : 0u;  cnt[k][1] += n1 ? 1u : 0u;
        cnt[k][2] += n2 ? 1u : 0u;  cnt[k][3] += n3 ? 1u : 0u;
        if (lane < 4) {
          unsigned long long bq = (lane == 0) ? b0 : (lane == 1) ? b1
                                : (lane == 2) ? b2 : b3;
          st[wave][k * 4 + lane][g + u] = bq;
        }
      }
    }
  }
  // flush 64 rows x 32 words: coalesced 512B column-major stores (own slice)
#pragma unroll
  for (int w = 0; w < 32; ++w)
    maskT[(size_t)(p0 + w) * N + r0 + lane] = st[wave][w][lane];

  // block-reduce degree counts: reuse st as uint scratch (32 KB of 64 KB)
  __syncthreads();
  unsigned int* sred = (unsigned int*)&st[0][0][0];
#pragma unroll
  for (int k = 0; k < 8; ++k) {
    uint4 c4; c4.x = cnt[k][0]; c4.y = cnt[k][1]; c4.z = cnt[k][2]; c4.w = cnt[k][3];
    *(uint4*)(sred + wave * CB + k * 256 + 4 * lane) = c4;   // col = k*256+4*lane+q
  }
  __syncthreads();
  for (int c = threadIdx.x; c < CB; c += 256) {
    unsigned int sum = sred[c] + sred[CB + c] + sred[2 * CB + c] + sred[3 * CB + c];
    deg_part[(size_t)blockIdx.y * N + jb + c] = sum;
  }
}

// fallback (no workspace): column-parallel degree only, atomics
__global__ void k_deg_only(const float* __restrict__ A,
                           unsigned int* __restrict__ deg) {
  int j = blockIdx.x * 256 + threadIdx.x;
  int i0 = blockIdx.y * 512;
  unsigned int cnt = 0;
#pragma unroll 4
  for (int i = i0; i < i0 + 512; ++i) {
    float a = A[(size_t)i * N + j];
    cnt += (a != 0.f) ? 1u : 0u;
  }
  atomicAdd(&deg[j], cnt);
}

// ---------- fused: deg reduce + dinv + z = x@W1 + wz = dinv*z ----------
__global__ void k_dinvz(const unsigned int* __restrict__ deg_part, int nparts,
                        const float* __restrict__ x, const float* __restrict__ W1,
                        float* __restrict__ dinv, float* __restrict__ z,
                        float* __restrict__ wz) {
  int i = blockIdx.x * 64 + threadIdx.x;
  unsigned int dsum = 0;
#pragma unroll 8
  for (int w = 0; w < nparts; ++w) dsum += deg_part[(size_t)w * N + i];
  float d = rsqrtf((float)(dsum + 1u));        // +1 self-loop
  dinv[i] = d;
  float zz[16];
#pragma unroll
  for (int c = 0; c < 16; ++c) zz[c] = 0.f;
  const float4* xr = (const float4*)(x + (size_t)i * F_IN);
#pragma unroll
  for (int k4 = 0; k4 < 16; ++k4) {
    float4 v = xr[k4];
#pragma unroll
    for (int c = 0; c < 16; ++c) {
      zz[c] += v.x * W1[(4 * k4 + 0) * HID + c];
      zz[c] += v.y * W1[(4 * k4 + 1) * HID + c];
      zz[c] += v.z * W1[(4 * k4 + 2) * HID + c];
      zz[c] += v.w * W1[(4 * k4 + 3) * HID + c];
    }
  }
  float4* z4 = (float4*)(z + (size_t)i * HID);
  float4* w4 = (float4*)(wz + (size_t)i * HID);
#pragma unroll
  for (int q = 0; q < 4; ++q) {
    float4 a; a.x = zz[4*q]; a.y = zz[4*q+1]; a.z = zz[4*q+2]; a.w = zz[4*q+3];
    z4[q] = a;
    float4 b; b.x = a.x * d; b.y = a.y * d; b.z = a.z * d; b.w = a.w * d;
    w4[q] = b;
  }
}

// ---------- s partials: lane owns a row, iterate a p-chunk coalesced ----------
__global__ void k_rowsum_T(const unsigned long long* __restrict__ maskT,
                           const float* __restrict__ dinv,
                           float* __restrict__ s_part) {
  int wave = threadIdx.x >> 6, lane = threadIdx.x & 63;
  int rg = blockIdx.x >> 1;                    // row group [0,256)
  int pc = (blockIdx.x & 1) * 4 + wave;        // p-chunk [0,8)
  int row = rg * 64 + lane;
  int pbase = pc * PW;
  float acc = 0.f;
#pragma unroll 1
  for (int b = 0; b < PW / 8; ++b) {
    unsigned long long w[8];
#pragma unroll
    for (int u = 0; u < 8; ++u)
      w[u] = maskT[(size_t)(pbase + b * 8 + u) * N + row];
#pragma unroll
    for (int u = 0; u < 8; ++u) {
      int p = pbase + b * 8 + u;
      unsigned long long wd = w[u];
      while (wd) {
        int bb = __builtin_ctzll(wd);
        wd &= wd - 1;
        acc += dinv[perm_col(p, bb)];
      }
    }
  }
  s_part[(size_t)pc * N + row] = acc;
}

__global__ void k_rowsum_direct(const float* __restrict__ A,
                                const float* __restrict__ dinv,
                                float* __restrict__ s) {
  int wave = threadIdx.x >> 6, lane = threadIdx.x & 63;
  int i = blockIdx.x * 4 + wave;
  const float* Ar = A + (size_t)i * N;
  float acc = 0.f;
  for (int t = 0; t < N; t += 64) {
    float a = Ar[t + lane];
    if (a != 0.f) acc += dinv[t + lane];
  }
#pragma unroll
  for (int off = 32; off > 0; off >>= 1) acc += __shfl_down(acc, off);
  if (lane == 0) s[i] = acc;
}

// ---------- SpMM partials: wave owns word-position p; rowmask walk ----------
__global__ void k_spmm_T(const unsigned long long* __restrict__ maskT,
                         const float* __restrict__ wz,
                         float* __restrict__ t_part) {
  int p = blockIdx.x * 4 + (threadIdx.x >> 6); // word position [0,256)
  int lane = threadIdx.x & 63;
  int i0 = blockIdx.y * RPC;
  const unsigned long long* mcol = maskT + (size_t)p * N + i0;
  float acc[16];
#pragma unroll
  for (int c = 0; c < 16; ++c) acc[c] = 0.f;
  unsigned long long wv = mcol[lane];          // batch 0, coalesced 512B
#pragma unroll 1
  for (int batch = 0; batch < RPC / 64; ++batch) {
    unsigned long long wnext = (batch + 1 < RPC / 64)
                             ? mcol[(batch + 1) * 64 + lane] : 0ull;
    int ib = i0 + batch * 64;
    unsigned long long rowmask = __ballot(wv != 0ull);
    while (rowmask) {
      int l = __builtin_ctzll(rowmask);
      rowmask &= rowmask - 1;
      unsigned long long wd = readlane64(wv, l);   // uniform word for row ib+l
      if ((wd >> lane) & 1ull) {
        const float4* wr = (const float4*)(wz + (size_t)(ib + l) * HID);
#pragma unroll
        for (int q = 0; q < 4; ++q) {
          float4 v = wr[q];
          acc[q * 4 + 0] += v.x; acc[q * 4 + 1] += v.y;
          acc[q * 4 + 2] += v.z; acc[q * 4 + 3] += v.w;
        }
      }
    }
    wv = wnext;
  }
  int t = blockIdx.x * 256 + threadIdx.x;      // = p*64 + lane
  float4* tp = (float4*)t_part;
#pragma unroll
  for (int q = 0; q < 4; ++q) {
    float4 v = make_float4(acc[q * 4 + 0], acc[q * 4 + 1],
                           acc[q * 4 + 2], acc[q * 4 + 3]);
    tp[((size_t)blockIdx.y * 4 + q) * N + t] = v;   // coalesced
  }
}

__global__ void k_spmm_direct(const float* __restrict__ A,
                              const float* __restrict__ wz,
                              float* __restrict__ t_part) {
  int j = blockIdx.x * 256 + threadIdx.x;
  int i0 = blockIdx.y * RPC;
  float acc[16];
#pragma unroll
  for (int c = 0; c < 16; ++c) acc[c] = 0.f;
  for (int i = i0; i < i0 + RPC; ++i) {
    float a = A[(size_t)i * N + j];
    if (a != 0.f) {
      const float4* wr = (const float4*)(wz + (size_t)i * HID);
#pragma unroll
      for (int q = 0; q < 4; ++q) {
        float4 v = wr[q];
        acc[q * 4 + 0] += v.x; acc[q * 4 + 1] += v.y;
        acc[q * 4 + 2] += v.z; acc[q * 4 + 3] += v.w;
      }
    }
  }
  float4* tp = (float4*)t_part;
#pragma unroll
  for (int q = 0; q < 4; ++q) {
    float4 v = make_float4(acc[q * 4 + 0], acc[q * 4 + 1],
                           acc[q * 4 + 2], acc[q * 4 + 3]);
    tp[((size_t)blockIdx.y * 4 + q) * N + j] = v;
  }
}

// ---------- combine partials, relu, u partial per block (64-thr blocks) ----------
__global__ void k_combine(const float* __restrict__ t_part,
                          const float* __restrict__ z,
                          const float* __restrict__ dinv,
                          const float* __restrict__ sp, int nsch,
                          const float* __restrict__ b1,
                          float* __restrict__ u_part, int perm) {
  int t = blockIdx.x * 64 + threadIdx.x;
  int lane = threadIdx.x & 63;
  int col = perm ? perm_col(t >> 6, t & 63) : t;
  const float4* tp = (const float4*)t_part;
  float acc[16];
#pragma unroll
  for (int c = 0; c < 16; ++c) acc[c] = 0.f;
#pragma unroll
  for (int ch = 0; ch < RCHUNK; ++ch) {
#pragma unroll
    for (int q = 0; q < 4; ++q) {
      float4 v = tp[((size_t)ch * 4 + q) * N + t];
      acc[q * 4 + 0] += v.x; acc[q * 4 + 1] += v.y;
      acc[q * 4 + 2] += v.z; acc[q * 4 + 3] += v.w;
    }
  }
  float zz[16];
  const float4* zr = (const float4*)(z + (size_t)col * HID);
#pragma unroll
  for (int q = 0; q < 4; ++q) {
    float4 v = zr[q];
    zz[q * 4 + 0] = v.x; zz[q * 4 + 1] = v.y; zz[q * 4 + 2] = v.z; zz[q * 4 + 3] = v.w;
  }
  float sv = 0.f;
#pragma unroll 8
  for (int sc = 0; sc < nsch; ++sc) sv += sp[(size_t)sc * N + col];
  float d = dinv[col];
  float rj = d * (d + sv);
  float uc[16];
#pragma unroll
  for (int c = 0; c < 16; ++c) {
    float pre = d * (d * zz[c] + acc[c]) + b1[c];
    float h = pre > 0.f ? pre : 0.f;
    uc[c] = rj * h;
  }
#pragma unroll
  for (int c = 0; c < 16; ++c) {
#pragma unroll
    for (int off = 32; off > 0; off >>= 1) uc[c] += __shfl_down(uc[c], off);
  }
  if (lane == 0) {
#pragma unroll
    for (int c = 0; c < 16; ++c) u_part[blockIdx.x * 16 + c] = uc[c];
  }
}

// ---------- final: u = sum of 256 u_part blocks; out = u @ W2 + N*b2 ----------
__global__ void k_final(const float* __restrict__ u_part,
                        const float* __restrict__ W2,
                        const float* __restrict__ b2,
                        float* __restrict__ out) {
  __shared__ float red[16][17];
  __shared__ float u[16];
  int t = threadIdx.x;                 // 256 threads
  int c = t & 15, g = t >> 4;          // 16 groups x 16 blocks each
  float a = 0.f;
#pragma unroll
  for (int b = 0; b < 16; ++b) a += u_part[(size_t)(g * 16 + b) * 16 + c];
  red[g][c] = a;
  __syncthreads();
  if (t < 16) {
    float s = 0.f;
#pragma unroll
    for (int g2 = 0; g2 < 16; ++g2) s += red[g2][t];
    u[t] = s;
  }
  __syncthreads();
  if (t < 32) {
    float o = (float)N * b2[t];
#pragma unroll
    for (int c2 = 0; c2 < 16; ++c2) o += u[c2] * W2[c2 * F_OUT + t];
    out[t] = o;
  }
}

extern "C" void kernel_launch(void* const* d_in, const int* in_sizes, int n_in,
                              void* d_out, int out_size, void* d_ws, size_t ws_size,
                              hipStream_t stream) {
  const float* A  = (const float*)d_in[0];
  const float* x  = (const float*)d_in[1];
  const float* W1 = (const float*)d_in[2];
  const float* b1 = (const float*)d_in[3];
  const float* W2 = (const float*)d_in[4];
  const float* b2 = (const float*)d_in[5];
  float* out = (float*)d_out;

  char* ws = (char*)d_ws;
  size_t off = 0;
  auto alloc = [&](size_t bytes) {
    char* p = ws + off;
    off += (bytes + 255) & ~(size_t)255;
    return p;
  };

  unsigned int* deg_part = (unsigned int*)alloc((size_t)NPART * N * 4);
  float* dinv       = (float*)alloc((size_t)N * 4);
  float* s_part     = (float*)alloc((size_t)PCH * N * 4);
  float* z          = (float*)alloc((size_t)N * HID * 4);
  float* wz         = (float*)alloc((size_t)N * HID * 4);
  float* u_part     = (float*)alloc(256 * 16 * 4);
  float* t_part     = (float*)alloc((size_t)RCHUNK * N * HID * 4);
  unsigned long long* maskT = (unsigned long long*)alloc((size_t)N * NWORDS * 8);
  bool use_mask = (ws_size >= off);   // ~55 MB needed for the mask path

  if (use_mask) {
    k_mask_deg<<<dim3(NXB, RY), 256, 0, stream>>>(A, maskT, deg_part);
    k_dinvz<<<N / 64, 64, 0, stream>>>(deg_part, NPART, x, W1, dinv, z, wz);
    k_rowsum_T<<<512, 256, 0, stream>>>(maskT, dinv, s_part);
    k_spmm_T<<<dim3(64, RCHUNK), 256, 0, stream>>>(maskT, wz, t_part);
    k_combine<<<N / 64, 64, 0, stream>>>(t_part, z, dinv, s_part, PCH, b1, u_part, 1);
  } else {
    hipMemsetAsync(deg_part, 0, (size_t)N * 4, stream);
    k_deg_only<<<dim3(64, 32), 256, 0, stream>>>(A, deg_part);
    k_dinvz<<<N / 64, 64, 0, stream>>>(deg_part, 1, x, W1, dinv, z, wz);
    k_rowsum_direct<<<N / 4, 256, 0, stream>>>(A, dinv, s_part);
    k_spmm_direct<<<dim3(64, RCHUNK), 256, 0, stream>>>(A, wz, t_part);
    k_combine<<<N / 64, 64, 0, stream>>>(t_part, z, dinv, s_part, 1, b1, u_part, 0);
  }
  k_final<<<1, 256, 0, stream>>>(u_part, W2, b2, out);
}